// Round 8
// baseline (363.441 us; speedup 1.0000x reference)
//
#include <hip/hip_runtime.h>
#include <hip/hip_bf16.h>

typedef unsigned short u16;
typedef __attribute__((ext_vector_type(8))) _Float16 half8;
typedef __attribute__((ext_vector_type(4))) float f32x4;

#define LOG2E 1.44269504088896340736f

__device__ __forceinline__ u16 f2h(float f) {
  _Float16 h = (_Float16)f;
  union { _Float16 h; u16 u; } a; a.h = h;
  return a.u;
}

__device__ __forceinline__ float h2f(u16 u) {
  union { _Float16 h; u16 u; } a; a.u = u;
  return (float)a.h;
}

__device__ __forceinline__ float silu_f(float y) {
  return y / (1.0f + __expf(-y));
}

// monotone uint encoding of float for atomicMax
__device__ __forceinline__ unsigned fenc(float f) {
  unsigned b = __float_as_uint(f);
  return (b & 0x80000000u) ? ~b : (b | 0x80000000u);
}
__device__ __forceinline__ float fdec(unsigned u) {
  unsigned b = (u & 0x80000000u) ? (u ^ 0x80000000u) : ~u;
  return __uint_as_float(b);
}

// async global->LDS, 16B per lane; LDS dest = wave-uniform base + lane*16
__device__ __forceinline__ void glds16(const u16* g, u16* l) {
  __builtin_amdgcn_global_load_lds(
      (__attribute__((address_space(1))) unsigned*)(g),
      (__attribute__((address_space(3))) unsigned*)(l), 16, 0, 0);
}

enum { EPI_BNSILU_N = 0, EPI_QKEV, EPI_RAW_F16, EPI_LOGITS, EPI_BNSILU_RES_M };

// C[m,n] = sum_k A[m,k]*B[n,k]  (NT GEMM, K-contiguous operands)
// 128x128 tile, BK=32 (unpadded, global_load_lds), 4 waves, 4x4 16x16x32 fp16 MFMA.
// DUAL: A k<256 from A (batched); k>=256 from A2 (batch-shared, lda 256).
// 1-D grid 32*TILES, XCD-affinity decode (id&7 pins batch group to XCD).
// EPI_LOGITS additionally computes per-row max -> encoded atomicMax into rmax.
template<int EPI, bool DUAL, int TILES, int GX>
__global__ __launch_bounds__(256, 2)
void gemm_nt(const u16* __restrict__ A, long long a_bs, int lda,
             const u16* __restrict__ A2,
             const u16* __restrict__ B, long long b_bs, int ldb,
             void* __restrict__ C0, long long c_bs, int ldc,
             void* __restrict__ C1, void* __restrict__ C2,
             int K,
             const float* __restrict__ p0, const float* __restrict__ p1,
             const float* __restrict__ res, long long res_bs,
             unsigned* __restrict__ rmax)
{
  __shared__ u16 smem[8192];   // lA[4096] | lB[4096]; v-transpose slab reuses it
  u16* lA = smem;
  u16* lB = smem + 4096;

  const int id = blockIdx.x;
  const int bz = (id & 7) + 8 * (id / (8 * TILES));
  const int tt = (id >> 3) % TILES;
  const int bm = tt % GX;
  const int bn = tt / GX;
  const u16* Ab = A + (long long)bz * a_bs;
  const u16* Bb = B + (long long)bz * b_bs;
  const int m0 = bm * 128;
  const int n0 = bn * 128;
  const int t = threadIdx.x;
  const int lane = t & 63;
  const int w = t >> 6;
  const int wm = (w & 1) * 64;
  const int wn = (w >> 1) * 64;
  const int q = lane >> 4;
  const int lr = lane & 15;

  f32x4 acc[4][4];
#pragma unroll
  for (int i = 0; i < 4; ++i)
#pragma unroll
    for (int j = 0; j < 4; ++j)
      acc[i][j] = (f32x4){0.f, 0.f, 0.f, 0.f};

  const int lrow = lane >> 2;
  const int kch = (lane & 3) ^ ((lane >> 2) & 3) ^ ((lane >> 4) & 3);
  const int lk = kch * 8;
  const u16* aR0 = Ab + (long long)(m0 + 32 * w + lrow) * lda + lk;
  const u16* aR1 = aR0 + 16LL * lda;
  const u16* bR0 = Bb + (long long)(n0 + 32 * w + lrow) * ldb + lk;
  const u16* bR1 = bR0 + 16LL * ldb;
  const u16* a2R0 = nullptr; const u16* a2R1 = nullptr;
  if constexpr (DUAL) {
    a2R0 = A2 + (long long)(m0 + 32 * w + lrow) * 256 + lk;
    a2R1 = a2R0 + 16LL * 256;
  }
  u16* la0 = lA + w * 1024; u16* la1 = la0 + 512;
  u16* lb0 = lB + w * 1024; u16* lb1 = lb0 + 512;
  const int fpos = (q ^ (lr & 3) ^ ((lr >> 2) & 3)) * 8;

  for (int k0 = 0; k0 < K; k0 += 32) {
    __syncthreads();
    if (!DUAL || k0 < 256) {
      glds16(aR0 + k0, la0);
      glds16(aR1 + k0, la1);
    } else {
      glds16(a2R0 + (k0 - 256), la0);
      glds16(a2R1 + (k0 - 256), la1);
    }
    glds16(bR0 + k0, lb0);
    glds16(bR1 + k0, lb1);
    __syncthreads();
    half8 af[4], bfr[4];
#pragma unroll
    for (int i = 0; i < 4; ++i)
      af[i] = *(const half8*)&lA[(wm + i * 16 + lr) * 32 + fpos];
#pragma unroll
    for (int j = 0; j < 4; ++j)
      bfr[j] = *(const half8*)&lB[(wn + j * 16 + lr) * 32 + fpos];
#pragma unroll
    for (int i = 0; i < 4; ++i)
#pragma unroll
      for (int j = 0; j < 4; ++j)
        acc[i][j] = __builtin_amdgcn_mfma_f32_16x16x32_f16(af[i], bfr[j], acc[i][j], 0, 0, 0);
  }

  // ---- epilogues (C/D layout: col=lane&15, row=quad*4+reg) ----
  if constexpr (EPI == EPI_BNSILU_N) {
    u16* Cg = (u16*)C0 + (long long)bz * c_bs;
#pragma unroll
    for (int i = 0; i < 4; ++i)
#pragma unroll
      for (int j = 0; j < 4; ++j)
#pragma unroll
        for (int r = 0; r < 4; ++r) {
          const int m = m0 + wm + i * 16 + q * 4 + r;
          const int n = n0 + wn + j * 16 + lr;
          float v = acc[i][j][r];
          v = silu_f(v * (p0[n] * 0.99999500003749969f) + p1[n]);
          Cg[(long long)m * ldc + n] = f2h(v);
        }
  } else if constexpr (EPI == EPI_RAW_F16 || EPI == EPI_LOGITS) {
    u16* Cg = (u16*)C0 + (long long)bz * c_bs;
#pragma unroll
    for (int i = 0; i < 4; ++i)
#pragma unroll
      for (int j = 0; j < 4; ++j)
#pragma unroll
        for (int r = 0; r < 4; ++r) {
          const int m = m0 + wm + i * 16 + q * 4 + r;
          const int n = n0 + wn + j * 16 + lr;
          Cg[(long long)m * ldc + n] = f2h(acc[i][j][r]);
        }
    if constexpr (EPI == EPI_LOGITS) {
      // per-row max of this 128-col block half -> device atomicMax
#pragma unroll
      for (int i = 0; i < 4; ++i)
#pragma unroll
        for (int r = 0; r < 4; ++r) {
          float mx = fmaxf(fmaxf(acc[i][0][r], acc[i][1][r]),
                           fmaxf(acc[i][2][r], acc[i][3][r]));
          mx = fmaxf(mx, __shfl_xor(mx, 1));
          mx = fmaxf(mx, __shfl_xor(mx, 2));
          mx = fmaxf(mx, __shfl_xor(mx, 4));
          mx = fmaxf(mx, __shfl_xor(mx, 8));
          if (lr == 0)
            atomicMax(&rmax[bz * 1024 + m0 + wm + i * 16 + q * 4 + r], fenc(mx));
        }
    }
  } else if constexpr (EPI == EPI_BNSILU_RES_M) {
    float* Cg = (float*)C0 + (long long)bz * c_bs;
    const float* rg = res + (long long)bz * res_bs;
#pragma unroll
    for (int i = 0; i < 4; ++i)
#pragma unroll
      for (int j = 0; j < 4; ++j)
#pragma unroll
        for (int r = 0; r < 4; ++r) {
          const int m = m0 + wm + i * 16 + q * 4 + r;
          const int n = n0 + wn + j * 16 + lr;
          float v = acc[i][j][r];
          v = silu_f(v * (p0[m] * 0.99999500003749969f) + p1[m]);
          const long long idx = (long long)m * ldc + n;
          Cg[idx] = v + rg[idx];
        }
  } else {
    // EPI_QKEV: n-segment 0=q 1=k 2=e 3=v(transposed)
    const int seg = n0 >> 8;
    const int nb = n0 & 255;  // 0 or 128
    if (seg < 3) {
      u16* dst; long long bs; int ld2;
      if (seg == 0) { dst = (u16*)C0; bs = 262144; ld2 = 256; }
      else { dst = (u16*)C1 + (seg == 2 ? 256 : 0); bs = 524288; ld2 = 512; }
      dst += (long long)bz * bs;
#pragma unroll
      for (int i = 0; i < 4; ++i)
#pragma unroll
        for (int j = 0; j < 4; ++j)
#pragma unroll
          for (int r = 0; r < 4; ++r) {
            const int m = m0 + wm + i * 16 + q * 4 + r;
            const int col = wn + j * 16 + lr;
            float v = acc[i][j][r] + p0[n0 + col];
            dst[(long long)m * ld2 + nb + col] = f2h(v);
          }
    } else {
      // v[c, j] = Y[j, 768+c] + bv[c]: transpose via LDS, 32-row slabs, stride 132
      u16* dst = (u16*)C2 + (long long)bz * 262144;
#pragma unroll
      for (int s = 0; s < 4; ++s) {
        const int rbase = s * 32;
        __syncthreads();
        if (wm == (rbase & 64)) {
          const int ibase = (rbase & 32) >> 4;
#pragma unroll
          for (int ii = 0; ii < 2; ++ii) {
            const int i = ibase + ii;
#pragma unroll
            for (int j = 0; j < 4; ++j)
#pragma unroll
              for (int r = 0; r < 4; ++r) {
                const int row32 = i * 16 + q * 4 + r - (rbase & 32);
                const int col = wn + j * 16 + lr;
                float v = acc[i][j][r] + p0[768 + nb + col];
                smem[row32 * 132 + col] = f2h(v);
              }
          }
        }
        __syncthreads();
#pragma unroll
        for (int p = 0; p < 2; ++p) {
          const int lin = p * 256 + t;
          const int c = lin >> 2;
          const int mc = lin & 3;
          u16 tmp[8];
#pragma unroll
          for (int r8 = 0; r8 < 8; ++r8)
            tmp[r8] = smem[(mc * 8 + r8) * 132 + c];
          *(half8*)&dst[(long long)(nb + c) * 1024 + m0 + rbase + mc * 8] =
              *(const half8*)tmp;
        }
      }
    }
  }
}

// fused softmax + PV: O[i,c] = (1/l_i) * sum_j exp(P[i,j]-m_i) * V[c,j]
// A-fragments: direct global half8 loads of raw fp16 logits, exp'd in-register;
// row-sum l accumulated alongside (each block covers full K per row).
__global__ __launch_bounds__(256, 2)
void pv_softmax(const u16* __restrict__ P, const unsigned* __restrict__ rmaxu,
                const u16* __restrict__ V, u16* __restrict__ O) {
  __shared__ u16 smem[4096];   // B staging only
  const int id = blockIdx.x;
  const int bz = (id & 7) + 8 * (id / 128);  // TILES=16
  const int tt = (id >> 3) & 15;
  const int m0 = (tt & 7) * 128;   // GX=8
  const int n0 = (tt >> 3) * 128;
  const int t = threadIdx.x;
  const int lane = t & 63;
  const int w = t >> 6;
  const int wm = (w & 1) * 64;
  const int wn = (w >> 1) * 64;
  const int q = lane >> 4;
  const int lr = lane & 15;

  f32x4 acc[4][4];
#pragma unroll
  for (int i = 0; i < 4; ++i)
#pragma unroll
    for (int j = 0; j < 4; ++j)
      acc[i][j] = (f32x4){0.f, 0.f, 0.f, 0.f};

  const int lrow = lane >> 2;
  const int kch = (lane & 3) ^ ((lane >> 2) & 3) ^ ((lane >> 4) & 3);
  const int lk = kch * 8;
  const u16* bR0 = V + (long long)bz * 262144 +
                   (long long)(n0 + 32 * w + lrow) * 1024 + lk;
  const u16* bR1 = bR0 + 16 * 1024;
  u16* lb0 = smem + w * 1024; u16* lb1 = lb0 + 512;
  const int fpos = (q ^ (lr & 3) ^ ((lr >> 2) & 3)) * 8;

  const u16* Ab = P + (long long)bz * 1048576;
  const u16* pA[4];
  float ml[4], lsum[4];
#pragma unroll
  for (int i = 0; i < 4; ++i) {
    const int row = m0 + wm + i * 16 + lr;
    pA[i] = Ab + (long long)row * 1024 + q * 8;
    ml[i] = fdec(rmaxu[bz * 1024 + row]) * LOG2E;
    lsum[i] = 0.f;
  }

  for (int k0 = 0; k0 < 1024; k0 += 32) {
    __syncthreads();
    glds16(bR0 + k0, lb0);
    glds16(bR1 + k0, lb1);
    half8 paf[4];
#pragma unroll
    for (int i = 0; i < 4; ++i) {
      half8 raw = *(const half8*)(pA[i] + k0);
      float e[8];
#pragma unroll
      for (int u = 0; u < 8; ++u)
        e[u] = exp2f(fmaf((float)raw[u], LOG2E, -ml[i]));
      lsum[i] += ((e[0] + e[1]) + (e[2] + e[3])) + ((e[4] + e[5]) + (e[6] + e[7]));
#pragma unroll
      for (int u = 0; u < 8; ++u) paf[i][u] = (_Float16)e[u];
    }
    __syncthreads();
    half8 bfr[4];
#pragma unroll
    for (int j = 0; j < 4; ++j)
      bfr[j] = *(const half8*)&smem[(wn + j * 16 + lr) * 32 + fpos];
#pragma unroll
    for (int i = 0; i < 4; ++i)
#pragma unroll
      for (int j = 0; j < 4; ++j)
        acc[i][j] = __builtin_amdgcn_mfma_f32_16x16x32_f16(paf[i], bfr[j], acc[i][j], 0, 0, 0);
  }

  // row-sum: combine q-lane partials (j-chunks), broadcast via LDS to C-layout rows
#pragma unroll
  for (int i = 0; i < 4; ++i) {
    lsum[i] += __shfl_xor(lsum[i], 16);
    lsum[i] += __shfl_xor(lsum[i], 32);
  }
  __syncthreads();
  float* rowl = (float*)smem;
  if (lane < 16) {
#pragma unroll
    for (int i = 0; i < 4; ++i)
      rowl[wm + i * 16 + lane] = lsum[i];
  }
  __syncthreads();
  u16* Og = O + (long long)bz * 262144;
#pragma unroll
  for (int i = 0; i < 4; ++i)
#pragma unroll
    for (int r = 0; r < 4; ++r) {
      const int row = wm + i * 16 + q * 4 + r;
      const float inv = 1.0f / rowl[row];
#pragma unroll
      for (int j = 0; j < 4; ++j)
        Og[(long long)(m0 + row) * 256 + n0 + wn + j * 16 + lr] =
            f2h(acc[i][j][r] * inv);
    }
}

// x [B,512,1024] fp32 -> xT [B,1024,512] fp16 (token-major)
__global__ __launch_bounds__(256)
void transpose_x(const float* __restrict__ x, u16* __restrict__ xT) {
  __shared__ float tile[64][33];
  const int b = blockIdx.z;
  const int n0 = blockIdx.x * 32;
  const int d0 = blockIdx.y * 64;
  const int tx = threadIdx.x;
  const int ty = threadIdx.y;
  const float* src = x + (long long)b * 524288;
#pragma unroll
  for (int i = 0; i < 8; ++i)
    tile[ty + 8 * i][tx] = src[(long long)(d0 + ty + 8 * i) * 1024 + n0 + tx];
  __syncthreads();
  u16* dst = xT + (long long)b * 524288;
#pragma unroll
  for (int i = 0; i < 4; ++i) {
    const int n = ty + 8 * i;
    unsigned lo = (unsigned)f2h(tile[2 * tx][n]);
    unsigned hi = (unsigned)f2h(tile[2 * tx + 1][n]);
    *(unsigned*)&dst[(long long)(n0 + n) * 512 + d0 + 2 * tx] = lo | (hi << 16);
  }
}

// weights: w1 | stacked(wq,wk,we,wv) | w2 -> fp16; fused bias (fp32) qkev
__global__ __launch_bounds__(256)
void convert_w(const float* __restrict__ w1, const float* __restrict__ wq,
               const float* __restrict__ wk, const float* __restrict__ wv,
               const float* __restrict__ we, const float* __restrict__ w2,
               const float* __restrict__ bq, const float* __restrict__ bk,
               const float* __restrict__ be, const float* __restrict__ bv,
               u16* __restrict__ dstw, float* __restrict__ bbuf) {
  int id = blockIdx.x * 256 + threadIdx.x;
  if (id < 524288) {
    float v;
    if (id < 131072) v = w1[id];
    else if (id < 393216) {
      int s = id - 131072, o = s >> 8, c = s & 255;
      if (o < 256) v = wq[o * 256 + c];
      else if (o < 512) v = wk[(o - 256) * 256 + c];
      else if (o < 768) v = we[(o - 512) * 256 + c];
      else v = wv[(o - 768) * 256 + c];
    } else v = w2[id - 393216];
    dstw[id] = f2h(v);
  } else {
    int i = id - 524288;
    float v;
    if (i < 256) v = bq[i];
    else if (i < 512) v = bk[i - 256];
    else if (i < 768) v = be[i - 512];
    else v = bv[i - 768];
    bbuf[i] = v;
  }
}

// posT[n,c] = fp16(rel_h[c,n>>5] + rel_w[c,n&31]); also init rowmax to enc(-inf)
__global__ __launch_bounds__(256)
void pos_compute(const float* __restrict__ rh, const float* __restrict__ rw,
                 u16* __restrict__ posT, unsigned* __restrict__ rmaxu) {
  const int n = blockIdx.x;
  const int c = threadIdx.x;
  posT[n * 256 + c] = f2h(rh[c * 32 + (n >> 5)] + rw[c * 32 + (n & 31)]);
  const int idx = n * 256 + c;
  if (idx < 32768) rmaxu[idx] = 0x007fffffu;  // fenc(-inf)
}

extern "C" void kernel_launch(void* const* d_in, const int* in_sizes, int n_in,
                              void* d_out, int out_size, void* d_ws, size_t ws_size,
                              hipStream_t stream) {
  const float* x  = (const float*)d_in[0];
  const float* w1 = (const float*)d_in[1];
  const float* g1 = (const float*)d_in[2];
  const float* b1 = (const float*)d_in[3];
  const float* wq = (const float*)d_in[4];
  const float* bq = (const float*)d_in[5];
  const float* wk = (const float*)d_in[6];
  const float* bk = (const float*)d_in[7];
  const float* wv = (const float*)d_in[8];
  const float* bv = (const float*)d_in[9];
  const float* we = (const float*)d_in[10];
  const float* be = (const float*)d_in[11];
  const float* rh = (const float*)d_in[12];
  const float* rw = (const float*)d_in[13];
  const float* w2 = (const float*)d_in[14];
  const float* g2 = (const float*)d_in[15];
  const float* b2 = (const float*)d_in[16];
  float* out = (float*)d_out;
  char* ws = (char*)d_ws;

  // ---- workspace (256 MiB available) ----
  u16* xT       = (u16*)(ws + 0);           // [B,1024,512] f16   32 MiB
  u16* x1t      = (u16*)(ws + 33554432);    // [B,1024,256] f16   16 MiB
  u16* qbuf     = (u16*)(ws + 50331648);    // [B,1024,256] f16   16 MiB
  u16* kcat     = (u16*)(ws + 67108864);    // [B,1024,512] f16   32 MiB (k|e)
  u16* vbuf     = (u16*)(ws + 100663296);   // [B,256,1024] f16   16 MiB
  u16* outt     = (u16*)(ws + 117440512);   // [B,1024,256] f16   16 MiB
  u16* posT     = (u16*)(ws + 134217728);   // [1024,256]   f16  512 KiB
  u16* wbuf     = (u16*)(ws + 134742016);   // packed weights      1 MiB
  float* bbuf   = (float*)(ws + 135790592); // fused qkev bias     4 KiB
  unsigned* rmx = (unsigned*)(ws + 136314880); // [B,1024] row max 128 KiB
  u16* logits   = (u16*)(ws + 142606336);   // [B,1024,1024] f16  64 MiB

  u16* w1b    = wbuf;            // [256,512]
  u16* wqkve  = wbuf + 131072;   // [1024,256] stacked q|k|e|v
  u16* w2b    = wbuf + 393216;   // [512,256]

  transpose_x<<<dim3(32, 8, 32), dim3(32, 8), 0, stream>>>(x, xT);
  convert_w<<<dim3(2052), 256, 0, stream>>>(w1, wq, wk, wv, we, w2,
                                            bq, bk, be, bv, wbuf, bbuf);
  pos_compute<<<dim3(1024), 256, 0, stream>>>(rh, rw, posT, rmx);

  // cv1: x1t[n,c] = silu(bn(xT[n,:] . w1[c,:]))   M=1024 N=256 K=512
  gemm_nt<EPI_BNSILU_N, false, 16, 8><<<dim3(512), 256, 0, stream>>>(
      xT, 524288LL, 512, nullptr, w1b, 0LL, 512,
      x1t, 262144LL, 256, nullptr, nullptr, 512, g1, b1, nullptr, 0LL, nullptr);

  // fused qkev: Y[n,o] = x1t[n,:] . wqkve[o,:] + b[o]   M=1024 N=1024 K=256
  gemm_nt<EPI_QKEV, false, 64, 8><<<dim3(2048), 256, 0, stream>>>(
      x1t, 262144LL, 256, nullptr, wqkve, 0LL, 256,
      qbuf, 262144LL, 256, kcat, vbuf, 256, bbuf, nullptr, nullptr, 0LL, nullptr);

  // logits[i,j] = [q(b)|posT][i,:] . kcat[j,:]  + row-max atomics
  gemm_nt<EPI_LOGITS, true, 64, 8><<<dim3(2048), 256, 0, stream>>>(
      qbuf, 262144LL, 256, posT, kcat, 524288LL, 512,
      logits, 1048576LL, 1024, nullptr, nullptr, 512, nullptr, nullptr, nullptr, 0LL, rmx);

  // fused softmax+PV: outt[i,c] = softmax(logits[i,:]) . vbuf[c,:]
  pv_softmax<<<dim3(512), 256, 0, stream>>>(logits, rmx, vbuf, outt);

  // cv2 + residual: out = x + silu(bn(w2 . outt))   M=512 N=1024 K=256
  gemm_nt<EPI_BNSILU_RES_M, false, 32, 4><<<dim3(1024), 256, 0, stream>>>(
      w2b, 0LL, 256, nullptr, outt, 262144LL, 256,
      out, 524288LL, 1024, nullptr, nullptr, 256, g2, b2, x, 524288LL, nullptr);
}

// Round 9
// 333.844 us; speedup vs baseline: 1.0887x; 1.0887x over previous
//
#include <hip/hip_runtime.h>
#include <hip/hip_bf16.h>

typedef unsigned short u16;
typedef __attribute__((ext_vector_type(8))) _Float16 half8;
typedef __attribute__((ext_vector_type(4))) float f32x4;

__device__ __forceinline__ u16 f2h(float f) {
  _Float16 h = (_Float16)f;
  union { _Float16 h; u16 u; } a; a.h = h;
  return a.u;
}

__device__ __forceinline__ float h2f(u16 u) {
  union { _Float16 h; u16 u; } a; a.u = u;
  return (float)a.h;
}

__device__ __forceinline__ float silu_f(float y) {
  return y / (1.0f + __expf(-y));
}

// async global->LDS, 16B per lane; LDS dest = wave-uniform base + lane*16
__device__ __forceinline__ void glds16(const u16* g, u16* l) {
  __builtin_amdgcn_global_load_lds(
      (__attribute__((address_space(1))) unsigned*)(g),
      (__attribute__((address_space(3))) unsigned*)(l), 16, 0, 0);
}

enum { EPI_BNSILU_N = 0, EPI_QKEV, EPI_RAW_F16, EPI_BNSILU_RES_M };

// C[m,n] = sum_k A[m,k]*B[n,k]  (NT GEMM, K-contiguous operands)
// 128x128 tile, BK=32 (unpadded, global_load_lds), 4 waves, 4x4 16x16x32 fp16 MFMA.
// DUAL: A k<256 from A (batched); k>=256 from A2 (batch-shared, lda 256).
// 1-D grid 32*TILES, XCD-affinity decode (id&7 pins batch group to XCD).
// launch_bounds(256,3): 3 blocks/CU (120 unified regs/wave, 48KB LDS/CU) — round-7's
// (256,2) capped occupancy at 34% with no pipe saturated (latency-bound).
template<int EPI, bool DUAL, int TILES, int GX>
__global__ __launch_bounds__(256, 3)
void gemm_nt(const u16* __restrict__ A, long long a_bs, int lda,
             const u16* __restrict__ A2,
             const u16* __restrict__ B, long long b_bs, int ldb,
             void* __restrict__ C0, long long c_bs, int ldc,
             void* __restrict__ C1, void* __restrict__ C2,
             int K,
             const float* __restrict__ p0, const float* __restrict__ p1,
             const float* __restrict__ res, long long res_bs)
{
  __shared__ u16 smem[8192];   // lA[4096] | lB[4096]; v-transpose slab reuses it
  u16* lA = smem;
  u16* lB = smem + 4096;

  const int id = blockIdx.x;
  const int bz = (id & 7) + 8 * (id / (8 * TILES));
  const int tt = (id >> 3) % TILES;
  const int bm = tt % GX;
  const int bn = tt / GX;
  const u16* Ab = A + (long long)bz * a_bs;
  const u16* Bb = B + (long long)bz * b_bs;
  const int m0 = bm * 128;
  const int n0 = bn * 128;
  const int t = threadIdx.x;
  const int lane = t & 63;
  const int w = t >> 6;
  const int wm = (w & 1) * 64;
  const int wn = (w >> 1) * 64;
  const int q = lane >> 4;
  const int lr = lane & 15;

  f32x4 acc[4][4];
#pragma unroll
  for (int i = 0; i < 4; ++i)
#pragma unroll
    for (int j = 0; j < 4; ++j)
      acc[i][j] = (f32x4){0.f, 0.f, 0.f, 0.f};

  const int lrow = lane >> 2;
  const int kch = (lane & 3) ^ ((lane >> 2) & 3) ^ ((lane >> 4) & 3);
  const int lk = kch * 8;
  const u16* aR0 = Ab + (long long)(m0 + 32 * w + lrow) * lda + lk;
  const u16* aR1 = aR0 + 16LL * lda;
  const u16* bR0 = Bb + (long long)(n0 + 32 * w + lrow) * ldb + lk;
  const u16* bR1 = bR0 + 16LL * ldb;
  const u16* a2R0 = nullptr; const u16* a2R1 = nullptr;
  if constexpr (DUAL) {
    a2R0 = A2 + (long long)(m0 + 32 * w + lrow) * 256 + lk;
    a2R1 = a2R0 + 16LL * 256;
  }
  u16* la0 = lA + w * 1024; u16* la1 = la0 + 512;
  u16* lb0 = lB + w * 1024; u16* lb1 = lb0 + 512;
  const int fpos = (q ^ (lr & 3) ^ ((lr >> 2) & 3)) * 8;

  for (int k0 = 0; k0 < K; k0 += 32) {
    __syncthreads();
    if (!DUAL || k0 < 256) {
      glds16(aR0 + k0, la0);
      glds16(aR1 + k0, la1);
    } else {
      glds16(a2R0 + (k0 - 256), la0);
      glds16(a2R1 + (k0 - 256), la1);
    }
    glds16(bR0 + k0, lb0);
    glds16(bR1 + k0, lb1);
    __syncthreads();
    half8 af[4], bfr[4];
#pragma unroll
    for (int i = 0; i < 4; ++i)
      af[i] = *(const half8*)&lA[(wm + i * 16 + lr) * 32 + fpos];
#pragma unroll
    for (int j = 0; j < 4; ++j)
      bfr[j] = *(const half8*)&lB[(wn + j * 16 + lr) * 32 + fpos];
#pragma unroll
    for (int i = 0; i < 4; ++i)
#pragma unroll
      for (int j = 0; j < 4; ++j)
        acc[i][j] = __builtin_amdgcn_mfma_f32_16x16x32_f16(af[i], bfr[j], acc[i][j], 0, 0, 0);
  }

  // ---- epilogues (C/D layout: col=lane&15, row=quad*4+reg) ----
  if constexpr (EPI == EPI_BNSILU_N) {
    u16* Cg = (u16*)C0 + (long long)bz * c_bs;
#pragma unroll
    for (int i = 0; i < 4; ++i)
#pragma unroll
      for (int j = 0; j < 4; ++j)
#pragma unroll
        for (int r = 0; r < 4; ++r) {
          const int m = m0 + wm + i * 16 + q * 4 + r;
          const int n = n0 + wn + j * 16 + lr;
          float v = acc[i][j][r];
          v = silu_f(v * (p0[n] * 0.99999500003749969f) + p1[n]);
          Cg[(long long)m * ldc + n] = f2h(v);
        }
  } else if constexpr (EPI == EPI_RAW_F16) {
    u16* Cg = (u16*)C0 + (long long)bz * c_bs;
#pragma unroll
    for (int i = 0; i < 4; ++i)
#pragma unroll
      for (int j = 0; j < 4; ++j)
#pragma unroll
        for (int r = 0; r < 4; ++r) {
          const int m = m0 + wm + i * 16 + q * 4 + r;
          const int n = n0 + wn + j * 16 + lr;
          Cg[(long long)m * ldc + n] = f2h(acc[i][j][r]);
        }
  } else if constexpr (EPI == EPI_BNSILU_RES_M) {
    float* Cg = (float*)C0 + (long long)bz * c_bs;
    const float* rg = res + (long long)bz * res_bs;
#pragma unroll
    for (int i = 0; i < 4; ++i)
#pragma unroll
      for (int j = 0; j < 4; ++j)
#pragma unroll
        for (int r = 0; r < 4; ++r) {
          const int m = m0 + wm + i * 16 + q * 4 + r;
          const int n = n0 + wn + j * 16 + lr;
          float v = acc[i][j][r];
          v = silu_f(v * (p0[m] * 0.99999500003749969f) + p1[m]);
          const long long idx = (long long)m * ldc + n;
          Cg[idx] = v + rg[idx];
        }
  } else {
    // EPI_QKEV: n-segment 0=q 1=k 2=e 3=v(transposed)
    const int seg = n0 >> 8;
    const int nb = n0 & 255;  // 0 or 128
    if (seg < 3) {
      u16* dst; long long bs; int ld2;
      if (seg == 0) { dst = (u16*)C0; bs = 262144; ld2 = 256; }
      else { dst = (u16*)C1 + (seg == 2 ? 256 : 0); bs = 524288; ld2 = 512; }
      dst += (long long)bz * bs;
#pragma unroll
      for (int i = 0; i < 4; ++i)
#pragma unroll
        for (int j = 0; j < 4; ++j)
#pragma unroll
          for (int r = 0; r < 4; ++r) {
            const int m = m0 + wm + i * 16 + q * 4 + r;
            const int col = wn + j * 16 + lr;
            float v = acc[i][j][r] + p0[n0 + col];
            dst[(long long)m * ld2 + nb + col] = f2h(v);
          }
    } else {
      // v[c, j] = Y[j, 768+c] + bv[c]: transpose via LDS, 32-row slabs, stride 132
      u16* dst = (u16*)C2 + (long long)bz * 262144;
#pragma unroll
      for (int s = 0; s < 4; ++s) {
        const int rbase = s * 32;
        __syncthreads();
        if (wm == (rbase & 64)) {
          const int ibase = (rbase & 32) >> 4;
#pragma unroll
          for (int ii = 0; ii < 2; ++ii) {
            const int i = ibase + ii;
#pragma unroll
            for (int j = 0; j < 4; ++j)
#pragma unroll
              for (int r = 0; r < 4; ++r) {
                const int row32 = i * 16 + q * 4 + r - (rbase & 32);
                const int col = wn + j * 16 + lr;
                float v = acc[i][j][r] + p0[768 + nb + col];
                smem[row32 * 132 + col] = f2h(v);
              }
          }
        }
        __syncthreads();
#pragma unroll
        for (int p = 0; p < 2; ++p) {
          const int lin = p * 256 + t;
          const int c = lin >> 2;
          const int mc = lin & 3;
          u16 tmp[8];
#pragma unroll
          for (int r8 = 0; r8 < 8; ++r8)
            tmp[r8] = smem[(mc * 8 + r8) * 132 + c];
          *(half8*)&dst[(long long)(nb + c) * 1024 + m0 + rbase + mc * 8] =
              *(const half8*)tmp;
        }
      }
    }
  }
}

// x [B,512,1024] fp32 -> xT [B,1024,512] fp16 (token-major)
__global__ __launch_bounds__(256)
void transpose_x(const float* __restrict__ x, u16* __restrict__ xT) {
  __shared__ float tile[64][33];
  const int b = blockIdx.z;
  const int n0 = blockIdx.x * 32;
  const int d0 = blockIdx.y * 64;
  const int tx = threadIdx.x;
  const int ty = threadIdx.y;
  const float* src = x + (long long)b * 524288;
#pragma unroll
  for (int i = 0; i < 8; ++i)
    tile[ty + 8 * i][tx] = src[(long long)(d0 + ty + 8 * i) * 1024 + n0 + tx];
  __syncthreads();
  u16* dst = xT + (long long)b * 524288;
#pragma unroll
  for (int i = 0; i < 4; ++i) {
    const int n = ty + 8 * i;
    unsigned lo = (unsigned)f2h(tile[2 * tx][n]);
    unsigned hi = (unsigned)f2h(tile[2 * tx + 1][n]);
    *(unsigned*)&dst[(long long)(n0 + n) * 512 + d0 + 2 * tx] = lo | (hi << 16);
  }
}

// weights: w1 | stacked(wq,wk,we,wv) | w2 -> fp16; fused bias (fp32) qkev
__global__ __launch_bounds__(256)
void convert_w(const float* __restrict__ w1, const float* __restrict__ wq,
               const float* __restrict__ wk, const float* __restrict__ wv,
               const float* __restrict__ we, const float* __restrict__ w2,
               const float* __restrict__ bq, const float* __restrict__ bk,
               const float* __restrict__ be, const float* __restrict__ bv,
               u16* __restrict__ dstw, float* __restrict__ bbuf) {
  int id = blockIdx.x * 256 + threadIdx.x;
  if (id < 524288) {
    float v;
    if (id < 131072) v = w1[id];
    else if (id < 393216) {
      int s = id - 131072, o = s >> 8, c = s & 255;
      if (o < 256) v = wq[o * 256 + c];
      else if (o < 512) v = wk[(o - 256) * 256 + c];
      else if (o < 768) v = we[(o - 512) * 256 + c];
      else v = wv[(o - 768) * 256 + c];
    } else v = w2[id - 393216];
    dstw[id] = f2h(v);
  } else {
    int i = id - 524288;
    float v;
    if (i < 256) v = bq[i];
    else if (i < 512) v = bk[i - 256];
    else if (i < 768) v = be[i - 512];
    else v = bv[i - 768];
    bbuf[i] = v;
  }
}

// posT[n,c] = fp16(rel_h[c, n>>5] + rel_w[c, n&31])
__global__ __launch_bounds__(256)
void pos_compute(const float* __restrict__ rh, const float* __restrict__ rw,
                 u16* __restrict__ posT) {
  const int n = blockIdx.x;
  const int c = threadIdx.x;
  posT[n * 256 + c] = f2h(rh[c * 32 + (n >> 5)] + rw[c * 32 + (n & 31)]);
}

// in-place softmax on fp16 rows of 1024
__global__ __launch_bounds__(256)
void softmax_rows(u16* __restrict__ logits) {
  __shared__ float red[8];
  u16* p = logits + (long long)blockIdx.x * 1024;
  const int t = threadIdx.x;
  ushort4 raw = ((const ushort4*)p)[t];
  float v0 = h2f(raw.x), v1 = h2f(raw.y), v2 = h2f(raw.z), v3 = h2f(raw.w);
  float mx = fmaxf(fmaxf(v0, v1), fmaxf(v2, v3));
#pragma unroll
  for (int off = 32; off > 0; off >>= 1) mx = fmaxf(mx, __shfl_down(mx, off));
  const int lane = t & 63, w = t >> 6;
  if (lane == 0) red[w] = mx;
  __syncthreads();
  mx = fmaxf(fmaxf(red[0], red[1]), fmaxf(red[2], red[3]));
  float e0 = __expf(v0 - mx), e1 = __expf(v1 - mx),
        e2 = __expf(v2 - mx), e3 = __expf(v3 - mx);
  float s = e0 + e1 + e2 + e3;
#pragma unroll
  for (int off = 32; off > 0; off >>= 1) s += __shfl_down(s, off);
  if (lane == 0) red[4 + w] = s;
  __syncthreads();
  const float inv = 1.0f / (red[4] + red[5] + red[6] + red[7]);
  ushort4 o;
  o.x = f2h(e0 * inv); o.y = f2h(e1 * inv); o.z = f2h(e2 * inv); o.w = f2h(e3 * inv);
  ((ushort4*)p)[t] = o;
}

extern "C" void kernel_launch(void* const* d_in, const int* in_sizes, int n_in,
                              void* d_out, int out_size, void* d_ws, size_t ws_size,
                              hipStream_t stream) {
  const float* x  = (const float*)d_in[0];
  const float* w1 = (const float*)d_in[1];
  const float* g1 = (const float*)d_in[2];
  const float* b1 = (const float*)d_in[3];
  const float* wq = (const float*)d_in[4];
  const float* bq = (const float*)d_in[5];
  const float* wk = (const float*)d_in[6];
  const float* bk = (const float*)d_in[7];
  const float* wv = (const float*)d_in[8];
  const float* bv = (const float*)d_in[9];
  const float* we = (const float*)d_in[10];
  const float* be = (const float*)d_in[11];
  const float* rh = (const float*)d_in[12];
  const float* rw = (const float*)d_in[13];
  const float* w2 = (const float*)d_in[14];
  const float* g2 = (const float*)d_in[15];
  const float* b2 = (const float*)d_in[16];
  float* out = (float*)d_out;
  char* ws = (char*)d_ws;

  // ---- workspace (256 MiB available) ----
  u16* xT     = (u16*)(ws + 0);           // [B,1024,512] f16   32 MiB
  u16* x1t    = (u16*)(ws + 33554432);    // [B,1024,256] f16   16 MiB
  u16* qbuf   = (u16*)(ws + 50331648);    // [B,1024,256] f16   16 MiB
  u16* kcat   = (u16*)(ws + 67108864);    // [B,1024,512] f16   32 MiB (k|e)
  u16* vbuf   = (u16*)(ws + 100663296);   // [B,256,1024] f16   16 MiB
  u16* outt   = (u16*)(ws + 117440512);   // [B,1024,256] f16   16 MiB
  u16* posT   = (u16*)(ws + 134217728);   // [1024,256]   f16  512 KiB
  u16* wbuf   = (u16*)(ws + 134742016);   // packed weights      1 MiB
  float* bbuf = (float*)(ws + 135790592); // fused qkev bias     4 KiB
  u16* logits = (u16*)(ws + 142606336);   // [B,1024,1024] f16  64 MiB

  u16* w1b    = wbuf;            // [256,512]
  u16* wqkve  = wbuf + 131072;   // [1024,256] stacked q|k|e|v
  u16* w2b    = wbuf + 393216;   // [512,256]

  transpose_x<<<dim3(32, 8, 32), dim3(32, 8), 0, stream>>>(x, xT);
  convert_w<<<dim3(2052), 256, 0, stream>>>(w1, wq, wk, wv, we, w2,
                                            bq, bk, be, bv, wbuf, bbuf);
  pos_compute<<<dim3(1024), 256, 0, stream>>>(rh, rw, posT);

  // cv1: x1t[n,c] = silu(bn(xT[n,:] . w1[c,:]))   M=1024 N=256 K=512
  gemm_nt<EPI_BNSILU_N, false, 16, 8><<<dim3(512), 256, 0, stream>>>(
      xT, 524288LL, 512, nullptr, w1b, 0LL, 512,
      x1t, 262144LL, 256, nullptr, nullptr, 512, g1, b1, nullptr, 0LL);

  // fused qkev: Y[n,o] = x1t[n,:] . wqkve[o,:] + b[o]   M=1024 N=1024 K=256
  gemm_nt<EPI_QKEV, false, 64, 8><<<dim3(2048), 256, 0, stream>>>(
      x1t, 262144LL, 256, nullptr, wqkve, 0LL, 256,
      qbuf, 262144LL, 256, kcat, vbuf, 256, bbuf, nullptr, nullptr, 0LL);

  // logits[i,j] = [q(b)|posT][i,:] . kcat[j,:]   M=1024 N=1024 K=512 (dual A)
  gemm_nt<EPI_RAW_F16, true, 64, 8><<<dim3(2048), 256, 0, stream>>>(
      qbuf, 262144LL, 256, posT, kcat, 524288LL, 512,
      logits, 1048576LL, 1024, nullptr, nullptr, 512, nullptr, nullptr, nullptr, 0LL);

  // softmax in place over all 32K rows
  softmax_rows<<<dim3(32768), 256, 0, stream>>>(logits);

  // outt[i,c] = attn[i,:] . vbuf[c,:]   M=1024 N=256 K=1024
  gemm_nt<EPI_RAW_F16, false, 16, 8><<<dim3(512), 256, 0, stream>>>(
      logits, 1048576LL, 1024, nullptr, vbuf, 262144LL, 1024,
      outt, 262144LL, 256, nullptr, nullptr, 1024, nullptr, nullptr, nullptr, 0LL);

  // cv2 + residual: out = x + silu(bn(w2 . outt))   M=512 N=1024 K=256
  gemm_nt<EPI_BNSILU_RES_M, false, 32, 4><<<dim3(1024), 256, 0, stream>>>(
      w2b, 0LL, 256, nullptr, outt, 262144LL, 256,
      out, 524288LL, 1024, nullptr, nullptr, 256, g2, b2, x, 524288LL);
}